// Round 12
// baseline (470.656 us; speedup 1.0000x reference)
//
#include <hip/hip_runtime.h>
#include <hip/hip_bf16.h>

// Problem constants (from reference setup_inputs)
#define N_NODES 10000
#define N_EDGES 320000
#define DIM_D   128
#define DIM_H   256

// Output layout (flat f32 concat, element offsets):
#define Z_ELEMS   (N_NODES * DIM_H)           // 2,560,000
#define RW_ELEMS  ((size_t)N_NODES * N_NODES) // 100,000,000
#define OFF_Z1    ((size_t)Z_ELEMS)
#define OFF_Z2    ((size_t)2 * Z_ELEMS)
#define OFF_RW1   ((size_t)3 * Z_ELEMS)
#define OFF_RW2   (OFF_RW1 + RW_ELEMS)

// Workspace layout (byte offsets into d_ws)
//   rowsum : float[10000]        @ 0
//   cnt    : int[10000]          @ 40960
//   colp   : int[10000*128]      @ 81920      (ELL, stride 128)
//   valp   : float[10000*128]    @ 5201920    (raw edge weights)
#define WS_ROWSUM 0
#define WS_CNT    40960
#define WS_COLP   81920
#define WS_VALP   5201920
#define ELL_K     128

// gemm tiling: BM=128 rows x BN=64 cols per block (512 threads), K chunked 32
#define GEMM_RB 79                  // ceil(10000/128)
#define GEMM_CB 4                   // 256/64
#define GEMM_TOTAL (GEMM_RB * GEMM_CB)  // 316

typedef float f32x4 __attribute__((ext_vector_type(4)));

__device__ inline void nt_store4(float* p, float x, float y, float z, float w) {
    f32x4 t = {x, y, z, w};
    __builtin_nontemporal_store(t, (f32x4*)p);
}

// --- init: zero rowsum + cnt (81,920 B = 5120 float4) ------------------------
__global__ void init_kernel(float4* __restrict__ ws) {
    int i = blockIdx.x * blockDim.x + threadIdx.x;   // 10 blocks x 512 = 5120
    ws[i] = make_float4(0.f, 0.f, 0.f, 0.f);
}

// --- build: rowsum + ELL pack (raw weights; normalize at stage time) ---------
__global__ void build_kernel(const int* __restrict__ ei,
                             const float* __restrict__ ew,
                             float* __restrict__ rowsum,
                             int* __restrict__ cnt,
                             int* __restrict__ colp,
                             float* __restrict__ valp, int E) {
    int e = blockIdx.x * blockDim.x + threadIdx.x;
    if (e >= E) return;
    int s = ei[e];
    int d = ei[E + e];
    float w = ew[e];
    atomicAdd(&rowsum[s], w);
    int slot = atomicAdd(&cnt[s], 1);
    if (slot < ELL_K) {              // fits: max degree << 128 (passed R8-R11)
        colp[s * ELL_K + slot] = d;
        valp[s * ELL_K + slot] = w;
    }
}

// --- fused: gemm tiles (blocks 0..315) + rw rows (316..20315) ----------------
// rw block b: SINGLE destination row — blocks [0,10000) write rw1 rows,
// [10000,20000) write rw2 rows (R8's winning write geometry). The row's ~32
// (col, normalized val) pairs stage in LDS with a 512-entry flag bitmap
// (f4 -> owner t = f4&511, pass bit = f4>>9). Each thread then materializes
// its 5 float4 segments in REGISTERS (zero unless flagged) and NT-streams
// them — no per-element LDS round trip on the 800 MB store path.
__global__ __launch_bounds__(512) void fused_kernel(
        const float* __restrict__ rowsum,
        const int* __restrict__ cnt,
        const int* __restrict__ colp,
        const float* __restrict__ valp,
        float* __restrict__ rw1,
        float* __restrict__ rw2,
        const float* __restrict__ x,
        const float* __restrict__ W,
        float* __restrict__ out) {
    __shared__ float smem[128 * 33 + 32 * 64];   // 25,088 B (gemm sizes it)
    int t = threadIdx.x;

    if (blockIdx.x >= GEMM_TOTAL) {
        // ---------------- rw row path ----------------
        int b = blockIdx.x - GEMM_TOTAL;           // 0..19999
        int r = (b >= N_NODES) ? b - N_NODES : b;
        float* dst = ((b >= N_NODES) ? rw2 : rw1) + (size_t)r * N_NODES;

        int*   cols  = reinterpret_cast<int*>(smem);         // [128]
        float* vals  = smem + 128;                           // [128]
        int*   flags = reinterpret_cast<int*>(smem + 256);   // [512]

        flags[t] = 0;
        __syncthreads();

        int n = cnt[r];
        if (n > ELL_K) n = ELL_K;
        if (t < n) {
            int c   = colp[r * ELL_K + t];
            float w = valp[r * ELL_K + t];
            cols[t] = c;
            vals[t] = w / (rowsum[c] + 1e-20f);
            int f4 = c >> 2;
            atomicOr(&flags[f4 & 511], 1 << (f4 >> 9));
        }
        __syncthreads();

        int fl = flags[t];

#pragma unroll
        for (int p = 0; p < 5; ++p) {
            int f4 = t + 512 * p;
            if (p == 4 && t >= 452) break;       // 2500 float4 per row
            float a0 = 0.f, a1 = 0.f, a2 = 0.f, a3 = 0.f;
            if (fl & (1 << p)) {                 // rare: ~32 of 2500 segments
                for (int j = 0; j < n; ++j) {
                    int c = cols[j];
                    if ((c >> 2) == f4) {
                        float v = vals[j];
                        switch (c & 3) {
                            case 0: a0 += v; break;
                            case 1: a1 += v; break;
                            case 2: a2 += v; break;
                            default: a3 += v; break;
                        }
                    }
                }
            }
            nt_store4(dst + 4 * f4, a0, a1, a2, a3);
        }
        return;
    }

    // ---------------- gemm path ----------------
    float* xs  = smem;                 // [128][33] padded
    float* wsm = smem + 128 * 33;      // [32][64]

    int bid = blockIdx.x;              // 0..315
    int rb = bid >> 2;
    int cb = bid & 3;
    int r_base = rb * 128;
    int c_base = cb * 64;

    int tr = t >> 4;                   // 0..31 -> 4 rows each
    int tc = t & 15;                   // 0..15 -> 4 cols each

    float acc[4][4];
#pragma unroll
    for (int i = 0; i < 4; ++i)
#pragma unroll
        for (int j = 0; j < 4; ++j) acc[i][j] = 0.f;

    for (int k0 = 0; k0 < DIM_D; k0 += 32) {
#pragma unroll
        for (int q = t; q < 1024; q += 512) {
            int row = q >> 3;
            int c4  = q & 7;
            int grow = r_base + row;
            float4 f = (grow < N_NODES)
                ? *reinterpret_cast<const float4*>(x + (size_t)grow * DIM_D + k0 + c4 * 4)
                : make_float4(0.f, 0.f, 0.f, 0.f);
            float* dstp = xs + row * 33 + c4 * 4;
            dstp[0] = f.x; dstp[1] = f.y; dstp[2] = f.z; dstp[3] = f.w;
        }
        {
            int kk = t >> 4;
            int c4 = t & 15;
            float4 f = *reinterpret_cast<const float4*>(
                W + (size_t)(k0 + kk) * DIM_H + c_base + c4 * 4);
            *reinterpret_cast<float4*>(wsm + kk * 64 + c4 * 4) = f;
        }
        __syncthreads();

        for (int kk = 0; kk < 32; ++kk) {
            float4 w4 = *reinterpret_cast<const float4*>(wsm + kk * 64 + tc * 4);
#pragma unroll
            for (int i = 0; i < 4; ++i) {
                float a = xs[(tr * 4 + i) * 33 + kk];
                acc[i][0] += a * w4.x;
                acc[i][1] += a * w4.y;
                acc[i][2] += a * w4.z;
                acc[i][3] += a * w4.w;
            }
        }
        __syncthreads();
    }

#pragma unroll
    for (int i = 0; i < 4; ++i) {
        int row = r_base + tr * 4 + i;
        if (row >= N_NODES) continue;
        size_t o = (size_t)row * DIM_H + c_base + tc * 4;
        nt_store4(out + o,          acc[i][0], acc[i][1], acc[i][2], acc[i][3]);
        nt_store4(out + OFF_Z1 + o, acc[i][0], acc[i][1], acc[i][2], acc[i][3]);
        nt_store4(out + OFF_Z2 + o, acc[i][0], acc[i][1], acc[i][2], acc[i][3]);
    }
}

extern "C" void kernel_launch(void* const* d_in, const int* in_sizes, int n_in,
                              void* d_out, int out_size, void* d_ws, size_t ws_size,
                              hipStream_t stream) {
    const float* x      = (const float*)d_in[0];
    const int*   ei     = (const int*)d_in[1];    // (2,E): [0..E)=src, [E..2E)=dst
    const float* ew     = (const float*)d_in[2];
    const float* W_enc  = (const float*)d_in[3];
    float* out = (float*)d_out;

    char* ws = (char*)d_ws;
    float* rowsum = (float*)(ws + WS_ROWSUM);
    int*   cnt    = (int*)(ws + WS_CNT);
    int*   colp   = (int*)(ws + WS_COLP);
    float* valp   = (float*)(ws + WS_VALP);

    // 1) zero rowsum + cnt
    init_kernel<<<10, 512, 0, stream>>>(reinterpret_cast<float4*>(ws));

    // 2) rowsum + ELL pack
    build_kernel<<<(N_EDGES + 511) / 512, 512, 0, stream>>>(
        ei, ew, rowsum, cnt, colp, valp, N_EDGES);

    // 3) fused: gemm (316) + 20000 single-dest rw row blocks
    fused_kernel<<<GEMM_TOTAL + 2 * N_NODES, 512, 0, stream>>>(
        rowsum, cnt, colp, valp, out + OFF_RW1, out + OFF_RW2, x, W_enc, out);
}

// Round 13
// 213.423 us; speedup vs baseline: 2.2053x; 2.2053x over previous
//
#include <hip/hip_runtime.h>
#include <hip/hip_bf16.h>

// Problem constants (from reference setup_inputs)
#define N_NODES 10000
#define N_EDGES 320000
#define DIM_D   128
#define DIM_H   256

// Output layout (flat f32 concat, element offsets):
#define Z_ELEMS   (N_NODES * DIM_H)           // 2,560,000
#define RW_ELEMS  ((size_t)N_NODES * N_NODES) // 100,000,000
#define OFF_Z1    ((size_t)Z_ELEMS)
#define OFF_Z2    ((size_t)2 * Z_ELEMS)
#define OFF_RW1   ((size_t)3 * Z_ELEMS)
#define OFF_RW2   (OFF_RW1 + RW_ELEMS)

// Workspace layout (byte offsets into d_ws)
//   rowsum : float[10000]        @ 0
//   cnt    : int[10000]          @ 40960
//   colp   : int[10000*128]      @ 81920      (ELL, stride 128)
//   valp   : float[10000*128]    @ 5201920    (raw edge weights)
#define WS_ROWSUM 0
#define WS_CNT    40960
#define WS_COLP   81920
#define WS_VALP   5201920
#define ELL_K     128

// gemm tiling: BM=128 rows x BN=64 cols per block (512 threads), K chunked 32
#define GEMM_RB 79                  // ceil(10000/128)
#define GEMM_CB 4                   // 256/64
#define GEMM_TOTAL (GEMM_RB * GEMM_CB)  // 316
#define RW_BLOCKS (2 * N_NODES)     // 20000: rw blocks first, gemm appended

typedef float f32x4 __attribute__((ext_vector_type(4)));

__device__ inline void nt_store4(float* p, float x, float y, float z, float w) {
    f32x4 t = {x, y, z, w};
    __builtin_nontemporal_store(t, (f32x4*)p);
}

// --- init: zero rowsum + cnt (81,920 B = 5120 float4) ------------------------
__global__ void init_kernel(float4* __restrict__ ws) {
    int i = blockIdx.x * blockDim.x + threadIdx.x;   // 10 blocks x 512 = 5120
    ws[i] = make_float4(0.f, 0.f, 0.f, 0.f);
}

// --- build: rowsum + ELL pack (raw weights; normalize at scatter time) -------
__global__ void build_kernel(const int* __restrict__ ei,
                             const float* __restrict__ ew,
                             float* __restrict__ rowsum,
                             int* __restrict__ cnt,
                             int* __restrict__ colp,
                             float* __restrict__ valp, int E) {
    int e = blockIdx.x * blockDim.x + threadIdx.x;
    if (e >= E) return;
    int s = ei[e];
    int d = ei[E + e];
    float w = ew[e];
    atomicAdd(&rowsum[s], w);
    int slot = atomicAdd(&cnt[s], 1);
    if (slot < ELL_K) {              // never triggers at lambda=32
        colp[s * ELL_K + slot] = d;
        valp[s * ELL_K + slot] = w;
    }
}

// --- fused: rw rows (blocks 0..19999) + gemm tiles (blocks 20000..20315) -----
// rw block b: r = b>>1, dst = (b&1)? rw2 : rw1. Zero 40KB LDS row, scatter
// the row's ELL entries (normalize inline by COLUMN rowsum per the
// reference's broadcast), stream LDS -> global with nontemporal float4.
__global__ __launch_bounds__(512) void fused_kernel(
        const float* __restrict__ rowsum,
        const int* __restrict__ cnt,
        const int* __restrict__ colp,
        const float* __restrict__ valp,
        float* __restrict__ rw1,
        float* __restrict__ rw2,
        const float* __restrict__ x,
        const float* __restrict__ W,
        float* __restrict__ out) {
    __shared__ float smem[N_NODES];    // 40,000 B
    int t = threadIdx.x;

    if (blockIdx.x < RW_BLOCKS) {
        // ---------------- rw row path ----------------
        int b = blockIdx.x;
        int r = b >> 1;
        float* dst = ((b & 1) ? rw2 : rw1) + (size_t)r * N_NODES;

        float4* row4 = reinterpret_cast<float4*>(smem);
        const float4 z4 = make_float4(0.f, 0.f, 0.f, 0.f);
        row4[t]        = z4;
        row4[t + 512]  = z4;
        row4[t + 1024] = z4;
        row4[t + 1536] = z4;
        if (t < 452) row4[t + 2048] = z4;
        __syncthreads();

        int n = cnt[r];
        if (n > ELL_K) n = ELL_K;
        if (t < n) {
            int d  = colp[r * ELL_K + t];
            float w = valp[r * ELL_K + t];
            atomicAdd(&smem[d], w / (rowsum[d] + 1e-20f));
        }
        __syncthreads();

        float4 v;
        v = row4[t];        nt_store4(dst + 4 * t,          v.x, v.y, v.z, v.w);
        v = row4[t + 512];  nt_store4(dst + 4 * (t + 512),  v.x, v.y, v.z, v.w);
        v = row4[t + 1024]; nt_store4(dst + 4 * (t + 1024), v.x, v.y, v.z, v.w);
        v = row4[t + 1536]; nt_store4(dst + 4 * (t + 1536), v.x, v.y, v.z, v.w);
        if (t < 452) {
            v = row4[t + 2048]; nt_store4(dst + 4 * (t + 2048), v.x, v.y, v.z, v.w);
        }
        return;
    }

    // ---------------- gemm path ----------------
    float* xs  = smem;                 // [128][33] padded
    float* wsm = smem + 128 * 33;      // [32][64]

    int bid = blockIdx.x - RW_BLOCKS;  // 0..315
    int rb = bid >> 2;
    int cb = bid & 3;
    int r_base = rb * 128;
    int c_base = cb * 64;

    int tr = t >> 4;                   // 0..31 -> 4 rows each
    int tc = t & 15;                   // 0..15 -> 4 cols each

    float acc[4][4];
#pragma unroll
    for (int i = 0; i < 4; ++i)
#pragma unroll
        for (int j = 0; j < 4; ++j) acc[i][j] = 0.f;

    for (int k0 = 0; k0 < DIM_D; k0 += 32) {
#pragma unroll
        for (int q = t; q < 1024; q += 512) {
            int row = q >> 3;
            int c4  = q & 7;
            int grow = r_base + row;
            float4 f = (grow < N_NODES)
                ? *reinterpret_cast<const float4*>(x + (size_t)grow * DIM_D + k0 + c4 * 4)
                : make_float4(0.f, 0.f, 0.f, 0.f);
            float* dstp = xs + row * 33 + c4 * 4;
            dstp[0] = f.x; dstp[1] = f.y; dstp[2] = f.z; dstp[3] = f.w;
        }
        {
            int kk = t >> 4;
            int c4 = t & 15;
            float4 f = *reinterpret_cast<const float4*>(
                W + (size_t)(k0 + kk) * DIM_H + c_base + c4 * 4);
            *reinterpret_cast<float4*>(wsm + kk * 64 + c4 * 4) = f;
        }
        __syncthreads();

        for (int kk = 0; kk < 32; ++kk) {
            float4 w4 = *reinterpret_cast<const float4*>(wsm + kk * 64 + tc * 4);
#pragma unroll
            for (int i = 0; i < 4; ++i) {
                float a = xs[(tr * 4 + i) * 33 + kk];
                acc[i][0] += a * w4.x;
                acc[i][1] += a * w4.y;
                acc[i][2] += a * w4.z;
                acc[i][3] += a * w4.w;
            }
        }
        __syncthreads();
    }

#pragma unroll
    for (int i = 0; i < 4; ++i) {
        int row = r_base + tr * 4 + i;
        if (row >= N_NODES) continue;
        size_t o = (size_t)row * DIM_H + c_base + tc * 4;
        nt_store4(out + o,          acc[i][0], acc[i][1], acc[i][2], acc[i][3]);
        nt_store4(out + OFF_Z1 + o, acc[i][0], acc[i][1], acc[i][2], acc[i][3]);
        nt_store4(out + OFF_Z2 + o, acc[i][0], acc[i][1], acc[i][2], acc[i][3]);
    }
}

extern "C" void kernel_launch(void* const* d_in, const int* in_sizes, int n_in,
                              void* d_out, int out_size, void* d_ws, size_t ws_size,
                              hipStream_t stream) {
    const float* x      = (const float*)d_in[0];
    const int*   ei     = (const int*)d_in[1];    // (2,E): [0..E)=src, [E..2E)=dst
    const float* ew     = (const float*)d_in[2];
    const float* W_enc  = (const float*)d_in[3];
    float* out = (float*)d_out;

    char* ws = (char*)d_ws;
    float* rowsum = (float*)(ws + WS_ROWSUM);
    int*   cnt    = (int*)(ws + WS_CNT);
    int*   colp   = (int*)(ws + WS_COLP);
    float* valp   = (float*)(ws + WS_VALP);

    // 1) zero rowsum + cnt via kernel (no hipMemsetAsync -> no fill artifacts)
    init_kernel<<<10, 512, 0, stream>>>(reinterpret_cast<float4*>(ws));

    // 2) rowsum + ELL pack (raw weights)
    build_kernel<<<(N_EDGES + 511) / 512, 512, 0, stream>>>(
        ei, ew, rowsum, cnt, colp, valp, N_EDGES);

    // 3) fused: 20000 rw row blocks + 316 gemm blocks
    fused_kernel<<<RW_BLOCKS + GEMM_TOTAL, 512, 0, stream>>>(
        rowsum, cnt, colp, valp, out + OFF_RW1, out + OFF_RW2, x, W_enc, out);
}